// Round 12
// baseline (219.889 us; speedup 1.0000x reference)
//
#include <hip/hip_runtime.h>

#define DD 32
#define DFF 256
#define BATCH_N 32768
#define ROWS 64
#define THREADS 256
#define BD (BATCH_N * DD)
#define YPITCH 40  // ybf row pitch in u16 (80B)
#define YFP 33     // yf row pitch in f32

typedef __bf16 bf16x8 __attribute__((ext_vector_type(8)));
typedef __bf16 bf16x4 __attribute__((ext_vector_type(4)));
typedef float f32x4 __attribute__((ext_vector_type(4)));
typedef float f32x16 __attribute__((ext_vector_type(16)));

__device__ __forceinline__ unsigned short f2bf(float f) {
  unsigned int u = __builtin_bit_cast(unsigned int, f);
  u += 0x7FFFu + ((u >> 16) & 1u);  // RNE
  return (unsigned short)(u >> 16);
}

// ---------------- weight repack: f32 row-major -> bf16 MFMA-fragment layout ----
// mode 0 (16x16x32 A-frag): packed[((ks*NT+nt)*64+l)*8+j] = W[ks*32+(l>>4)*8+j][nt*16+(l&15)]
// mode 1 (32x32x16 A-frag): packed[((ks*NT+nt)*64+l)*8+j] = W[ks*16+(l>>5)*8+j][nt*32+(l&31)]
__global__ void repack_kernel(const float* __restrict__ src,
                              unsigned short* __restrict__ dst,
                              int K, int N, long sstride, long dstride, int mode) {
  long mat = blockIdx.y;
  int p = blockIdx.x * 256 + threadIdx.x;
  if (p >= K * N) return;
  int j = p & 7;
  int l = (p >> 3) & 63;
  int rest = p >> 9;
  int k, n;
  if (mode == 0) {
    int NT = N >> 4;
    int nt = rest % NT;
    int ks = rest / NT;
    k = ks * 32 + ((l >> 4) << 3) + j;
    n = nt * 16 + (l & 15);
  } else {
    int NT = N >> 5;
    int nt = rest % NT;
    int ks = rest / NT;
    k = ks * 16 + ((l >> 5) << 3) + j;
    n = nt * 32 + (l & 31);
  }
  dst[mat * dstride + p] = f2bf(src[mat * sstride + (long)k * N + n]);
}

// act: [64][256] bf16 row-major, XOR-swizzled
__device__ __forceinline__ int swzA(int row, int col) {
  return ((row * DFF + col) * 2) ^ ((row & 7) << 4);
}
__device__ __forceinline__ bf16x8 ldA(const unsigned short* buf, int row, int k0) {
  return __builtin_bit_cast(bf16x8, *(const uint4*)((const char*)buf + swzA(row, k0)));
}
__device__ __forceinline__ bf16x8 ldY(const unsigned short* ybf, int row, int k0) {
  return __builtin_bit_cast(bf16x8, *(const uint4*)(ybf + row * YPITCH + k0));
}
__device__ __forceinline__ uint4 ldWraw(const unsigned short* __restrict__ wp,
                                        int ks, int NT, int ntAbs, int lane) {
  return *(const uint4*)(wp + ((((ks * NT + ntAbs) << 6) + lane) << 3));
}
__device__ __forceinline__ bf16x8 asw(uint4 v) { return __builtin_bit_cast(bf16x8, v); }

#define MFMA16(a, b, c) __builtin_amdgcn_mfma_f32_16x16x32_bf16((a), (b), (c), 0, 0, 0)
#define MFMA32(a, b, c) __builtin_amdgcn_mfma_f32_32x32x16_bf16((a), (b), (c), 0, 0, 0)

// ---- 16x16 encoder helpers (unchanged, validated) ----
__device__ __forceinline__ void biasInit(f32x4 acc[4][4], const float* __restrict__ b,
                                         int ng, int lg) {
#pragma unroll
  for (int nt = 0; nt < 4; ++nt) {
    f32x4 bv = *(const f32x4*)(b + (ng * 4 + nt) * 16 + lg * 4);
#pragma unroll
    for (int rt = 0; rt < 4; ++rt) acc[nt][rt] = bv;
  }
}
__device__ __forceinline__ void storeAct(unsigned short* act, f32x4 acc[4][4],
                                         int ng, int lr, int lg) {
#pragma unroll
  for (int nt = 0; nt < 4; ++nt) {
    int n = (ng * 4 + nt) * 16 + lg * 4;
#pragma unroll
    for (int rt = 0; rt < 4; ++rt) {
      int r = rt * 16 + lr;
      bf16x4 w;
#pragma unroll
      for (int rr = 0; rr < 4; ++rr) w[rr] = (__bf16)fmaxf(acc[nt][rt][rr], 0.f);
      *(bf16x4*)((char*)act + swzA(r, n)) = w;
    }
  }
}

// ---- 32x32 decoder helpers ----
// acc2[nt][rt]: batch row = rt*32 + (lane&31); feature = ng*64 + nt*32 + (e&3) + 8*(e>>2) + 4*hi
__device__ __forceinline__ void biasInit32(f32x16 acc2[2][2], const float* __restrict__ b,
                                           int ng, int hi) {
#pragma unroll
  for (int nt = 0; nt < 2; ++nt) {
    f32x16 v;
#pragma unroll
    for (int g = 0; g < 4; ++g) {
      f32x4 bv = *(const f32x4*)(b + ng * 64 + nt * 32 + hi * 4 + g * 8);
#pragma unroll
      for (int c = 0; c < 4; ++c) v[g * 4 + c] = bv[c];
    }
    acc2[nt][0] = v;
    acc2[nt][1] = v;
  }
}
__device__ __forceinline__ void storeAct32(unsigned short* act, f32x16 acc2[2][2],
                                           int ng, int hi, int lane) {
#pragma unroll
  for (int nt = 0; nt < 2; ++nt) {
#pragma unroll
    for (int rt = 0; rt < 2; ++rt) {
      int r = rt * 32 + (lane & 31);
#pragma unroll
      for (int g = 0; g < 4; ++g) {
        int f = ng * 64 + nt * 32 + hi * 4 + g * 8;
        bf16x4 w;
#pragma unroll
        for (int c = 0; c < 4; ++c) w[c] = (__bf16)fmaxf(acc2[nt][rt][g * 4 + c], 0.f);
        *(bf16x4*)((char*)act + swzA(r, f)) = w;
      }
    }
  }
}

__global__ __launch_bounds__(THREADS, 2)
void vae_kernel(const float* __restrict__ xin, const float* __restrict__ eps,
                const float* __restrict__ be1, const float* __restrict__ be2,
                const float* __restrict__ be3, const float* __restrict__ b1,
                const float* __restrict__ b2, const float* __restrict__ W3,
                const float* __restrict__ b3,
                const unsigned short* __restrict__ We1p,
                const unsigned short* __restrict__ We2p,
                const unsigned short* __restrict__ We3p,
                const unsigned short* __restrict__ W1p,
                const unsigned short* __restrict__ W2p,
                float* __restrict__ out) {
  __shared__ __align__(16) unsigned short act[ROWS * DFF];  // 32 KB
  __shared__ unsigned short ybf[ROWS * YPITCH];             // 5 KB: masked y, bf16
  __shared__ float yf[ROWS * YFP];                          // 8.4 KB: y, f32
  __shared__ float red[4 * ROWS];                           // 1 KB: cross-ng W3 reduce

  // ---- phase-stagger co-resident blocks (R11: measured +5%) ----
  {
    unsigned units = ((blockIdx.x >> 8) & 1) * 2 + ((blockIdx.x >> 3) & 1);
    for (unsigned s = 0; s < units; ++s) __builtin_amdgcn_s_sleep(63);
  }

  const int tid = threadIdx.x;
  const int lane = tid & 63;
  const int ng = tid >> 6;   // wave = feature group: n in [ng*64, ng*64+63]
  const int lr = lane & 15;
  const int lg = lane >> 4;
  const int hi = lane >> 5;
  const long r0 = (long)blockIdx.x * ROWS;

  // ---- stage x into ybf ----
  for (int e = tid; e < ROWS * DD; e += THREADS) {
    int rr = e >> 5, d = e & 31;
    ybf[rr * YPITCH + d] = f2bf(xin[(r0 + rr) * DD + d]);
  }
  __syncthreads();

  f32x4 acc[4][4];

  // ---- enc1: h1 = relu(x @ We1 + be1) ----
  biasInit(acc, be1, ng, lg);
  {
    bf16x8 yb[4];
#pragma unroll
    for (int rt = 0; rt < 4; ++rt) yb[rt] = ldY(ybf, rt * 16 + lr, lg * 8);
#pragma unroll
    for (int nt = 0; nt < 4; ++nt) {
      bf16x8 w = asw(ldWraw(We1p, 0, 16, ng * 4 + nt, lane));
#pragma unroll
      for (int rt = 0; rt < 4; ++rt) acc[nt][rt] = MFMA16(w, yb[rt], acc[nt][rt]);
    }
  }
  storeAct(act, acc, ng, lr, lg);
  __syncthreads();

  // ---- enc2: h2 = relu(h1 @ We2 + be2), in place ----
  biasInit(acc, be2, ng, lg);
#pragma unroll
  for (int ks = 0; ks < 8; ++ks) {
    bf16x8 ab[4];
#pragma unroll
    for (int rt = 0; rt < 4; ++rt) ab[rt] = ldA(act, rt * 16 + lr, ks * 32 + lg * 8);
#pragma unroll
    for (int nt = 0; nt < 4; ++nt) {
      bf16x8 w = asw(ldWraw(We2p, ks, 16, ng * 4 + nt, lane));
#pragma unroll
      for (int rt = 0; rt < 4; ++rt) acc[nt][rt] = MFMA16(w, ab[rt], acc[nt][rt]);
    }
  }
  __syncthreads();
  storeAct(act, acc, ng, lr, lg);
  __syncthreads();

  // ---- enc3: z^T = We3^T @ h2^T + be3 -> f32 overlay zt[64][66] ----
  {
    f32x4 az[4];
    f32x4 bz = *(const f32x4*)(be3 + ng * 16 + lg * 4);
#pragma unroll
    for (int rt = 0; rt < 4; ++rt) az[rt] = bz;
#pragma unroll
    for (int ks = 0; ks < 8; ++ks) {
      bf16x8 w = asw(ldWraw(We3p, ks, 4, ng, lane));
#pragma unroll
      for (int rt = 0; rt < 4; ++rt) {
        bf16x8 a = ldA(act, rt * 16 + lr, ks * 32 + lg * 8);
        az[rt] = MFMA16(w, a, az[rt]);
      }
    }
    __syncthreads();  // all h2 reads complete before overlay write
    float* zt = (float*)act;  // [64 n][66 r] f32 = 16.9 KB
#pragma unroll
    for (int rt = 0; rt < 4; ++rt) {
      int r = rt * 16 + lr;
#pragma unroll
      for (int rr = 0; rr < 4; ++rr)
        zt[(ng * 16 + lg * 4 + rr) * 66 + r] = az[rt][rr];
    }
  }
  __syncthreads();

  // ---- reparam: y0 = mu + exp(lv/2)*eps; ybf = masked y (col 0 only) ----
  {
    const float* zt = (const float*)act;
    for (int e = tid; e < ROWS * DD; e += THREADS) {
      int rr = e >> 5, d = e & 31;
      float mu = zt[d * 66 + rr];
      float lv = zt[(32 + d) * 66 + rr];
      long gi = (r0 + rr) * DD + d;
      float y0 = mu + __expf(0.5f * lv) * eps[gi];
      yf[rr * YFP + d] = y0;
      ybf[rr * YPITCH + d] = (d == 0) ? f2bf(y0) : (unsigned short)0;
      out[BD + gi] = mu;
      out[2L * BD + gi] = lv;
    }
  }

  // ---- preload decoder weights for step 0 (32x32 fragment form, NT=8) ----
  uint4 w1f[2][2], w2f[8][2];
#pragma unroll
  for (int ks = 0; ks < 2; ++ks)
#pragma unroll
    for (int nt = 0; nt < 2; ++nt) w1f[ks][nt] = ldWraw(W1p, ks, 8, ng * 2 + nt, lane);
#pragma unroll
  for (int ks = 0; ks < 8; ++ks)
#pragma unroll
    for (int nt = 0; nt < 2; ++nt) w2f[ks][nt] = ldWraw(W2p, ks, 8, ng * 2 + nt, lane);
  __syncthreads();

  // ---- causal decoder: 32 sequential steps (32x32x16 MFMA) ----
#pragma unroll 1
  for (int i = 0; i < DD; ++i) {
    const unsigned short* W2cur = W2p + i * (DFF * DFF);
    const int inx = (i + 1 < DD) ? i + 1 : i;
    const unsigned short* W1nx = W1p + inx * (DD * DFF);
    const unsigned short* W2nx = W2p + inx * (DFF * DFF);

    f32x16 acc2[2][2];

    // phase A: t1 = relu(y_masked @ W1[i] + b1[i])
    biasInit32(acc2, b1 + i * DFF, ng, hi);
    {
      bf16x8 yb[2][2];
#pragma unroll
      for (int ks = 0; ks < 2; ++ks)
#pragma unroll
        for (int rt = 0; rt < 2; ++rt)
          yb[ks][rt] = ldY(ybf, rt * 32 + (lane & 31), ks * 16 + hi * 8);
#pragma unroll
      for (int ks = 0; ks < 2; ++ks)
#pragma unroll
        for (int nt = 0; nt < 2; ++nt) {
          bf16x8 w = asw(w1f[ks][nt]);
#pragma unroll
          for (int rt = 0; rt < 2; ++rt)
            acc2[nt][rt] = MFMA32(w, yb[ks][rt], acc2[nt][rt]);
        }
    }
    storeAct32(act, acc2, ng, hi, lane);
    __syncthreads();  // BAR1: t1 visible

    // phase B: t2 = relu(t1 @ W2[i] + b2[i]) in regs, fused with W3 dot.
    // w2f slots consumed from regs; refilled 8 ks-steps ahead.
    biasInit32(acc2, b2 + i * DFF, ng, hi);
#pragma unroll
    for (int ks = 0; ks < 8; ++ks) {
      bf16x8 ab[2];
#pragma unroll
      for (int rt = 0; rt < 2; ++rt)
        ab[rt] = ldA(act, rt * 32 + (lane & 31), ks * 16 + hi * 8);
#pragma unroll
      for (int nt = 0; nt < 2; ++nt) {
        bf16x8 w = asw(w2f[ks][nt]);
#pragma unroll
        for (int rt = 0; rt < 2; ++rt) acc2[nt][rt] = MFMA32(w, ab[rt], acc2[nt][rt]);
        w2f[ks][nt] = ldWraw(W2cur, ks + 8, 8, ng * 2 + nt, lane);  // refill ks+8 of step i
      }
    }
#pragma unroll
    for (int ks = 8; ks < 16; ++ks) {
      bf16x8 ab[2];
#pragma unroll
      for (int rt = 0; rt < 2; ++rt)
        ab[rt] = ldA(act, rt * 32 + (lane & 31), ks * 16 + hi * 8);
#pragma unroll
      for (int nt = 0; nt < 2; ++nt) {
        bf16x8 w = asw(w2f[ks - 8][nt]);
#pragma unroll
        for (int rt = 0; rt < 2; ++rt) acc2[nt][rt] = MFMA32(w, ab[rt], acc2[nt][rt]);
        w2f[ks - 8][nt] = ldWraw(W2nx, ks - 8, 8, ng * 2 + nt, lane);  // refill step i+1
      }
    }
#pragma unroll
    for (int ks = 0; ks < 2; ++ks)
#pragma unroll
      for (int nt = 0; nt < 2; ++nt) w1f[ks][nt] = ldWraw(W1nx, ks, 8, ng * 2 + nt, lane);

    // fused W3 dot: each lane holds 16 features of one batch row -> 1 shuffle reduce
    const float* w3r = W3 + i * DFF;
    float part[2] = {0.f, 0.f};
#pragma unroll
    for (int nt = 0; nt < 2; ++nt) {
#pragma unroll
      for (int g = 0; g < 4; ++g) {
        f32x4 w3v = *(const f32x4*)(w3r + ng * 64 + nt * 32 + hi * 4 + g * 8);
#pragma unroll
        for (int c = 0; c < 4; ++c) {
#pragma unroll
          for (int rt = 0; rt < 2; ++rt)
            part[rt] = fmaf(fmaxf(acc2[nt][rt][g * 4 + c], 0.f), w3v[c], part[rt]);
        }
      }
    }
#pragma unroll
    for (int rt = 0; rt < 2; ++rt) part[rt] += __shfl_xor(part[rt], 32);
    if (lane < 32) {
#pragma unroll
      for (int rt = 0; rt < 2; ++rt) red[ng * ROWS + rt * 32 + lane] = part[rt];
    }
    __syncthreads();  // BAR2: red visible

    if (tid < ROWS) {
      float v = b3[i] + red[tid] + red[ROWS + tid] + red[2 * ROWS + tid] + red[3 * ROWS + tid];
      yf[tid * YFP + i] = v;
      ybf[tid * YPITCH + i] = f2bf(v);
      if (i + 1 < DD)  // unmask next column (y0)
        ybf[tid * YPITCH + i + 1] = f2bf(yf[tid * YFP + i + 1]);
    }
    __syncthreads();  // BAR3: y state visible
  }

  // ---- final y -> outputs 0 and 3 ----
  for (int e = tid; e < ROWS * DD; e += THREADS) {
    int rr = e >> 5, d = e & 31;
    long gi = (r0 + rr) * DD + d;
    float v = yf[rr * YFP + d];
    out[gi] = v;
    out[3L * BD + gi] = v;
  }
}

extern "C" void kernel_launch(void* const* d_in, const int* in_sizes, int n_in,
                              void* d_out, int out_size, void* d_ws, size_t ws_size,
                              hipStream_t stream) {
  const float* xin = (const float*)d_in[0];
  // d_in[1] = m — unused by the reference
  const float* eps = (const float*)d_in[2];
  const float* We1 = (const float*)d_in[3];
  const float* be1 = (const float*)d_in[4];
  const float* We2 = (const float*)d_in[5];
  const float* be2 = (const float*)d_in[6];
  const float* We3 = (const float*)d_in[7];
  const float* be3 = (const float*)d_in[8];
  const float* W1  = (const float*)d_in[9];
  const float* b1  = (const float*)d_in[10];
  const float* W2  = (const float*)d_in[11];
  const float* b2  = (const float*)d_in[12];
  const float* W3  = (const float*)d_in[13];
  const float* b3  = (const float*)d_in[14];
  float* out = (float*)d_out;

  // packed bf16 weights in workspace (~4.9 MB)
  unsigned short* We1p = (unsigned short*)d_ws;
  unsigned short* We2p = We1p + 32 * 256;
  unsigned short* We3p = We2p + 256 * 256;
  unsigned short* W1p  = We3p + 256 * 64;
  unsigned short* W2p  = W1p + 32 * 32 * 256;

  repack_kernel<<<dim3(32, 1), 256, 0, stream>>>(We1, We1p, 32, 256, 0, 0, 0);
  repack_kernel<<<dim3(256, 1), 256, 0, stream>>>(We2, We2p, 256, 256, 0, 0, 0);
  repack_kernel<<<dim3(64, 1), 256, 0, stream>>>(We3, We3p, 256, 64, 0, 0, 0);
  repack_kernel<<<dim3(32, 32), 256, 0, stream>>>(W1, W1p, 32, 256, 32 * 256, 32 * 256, 1);
  repack_kernel<<<dim3(256, 32), 256, 0, stream>>>(W2, W2p, 256, 256, 256 * 256, 256 * 256, 1);

  vae_kernel<<<dim3(BATCH_N / ROWS), THREADS, 0, stream>>>(
      xin, eps, be1, be2, be3, b1, b2, W3, b3, We1p, We2p, We3p, W1p, W2p, out);
}

// Round 13
// 201.641 us; speedup vs baseline: 1.0905x; 1.0905x over previous
//
#include <hip/hip_runtime.h>

#define DD 32
#define DFF 256
#define BATCH_N 32768
#define ROWS 64
#define THREADS 256
#define BD (BATCH_N * DD)
#define YPITCH 40  // ybf row pitch in u16 (80B)
#define YFP 33     // yf row pitch in f32

typedef __bf16 bf16x8 __attribute__((ext_vector_type(8)));
typedef __bf16 bf16x4 __attribute__((ext_vector_type(4)));
typedef float f32x4 __attribute__((ext_vector_type(4)));

__device__ __forceinline__ unsigned short f2bf(float f) {
  unsigned int u = __builtin_bit_cast(unsigned int, f);
  u += 0x7FFFu + ((u >> 16) & 1u);  // RNE
  return (unsigned short)(u >> 16);
}

// ---------------- weight repack: f32 row-major -> bf16 MFMA-fragment layout ----
// packed[((ks*NT + nt)*64 + l)*8 + j] = W[ks*32 + (l>>4)*8 + j][nt*16 + (l&15)]
// (used as MFMA A operand: lane l holds W^T[n = nt*16 + (l&15)][k])
__global__ void repack_kernel(const float* __restrict__ src,
                              unsigned short* __restrict__ dst,
                              int K, int N, long sstride, long dstride) {
  long mat = blockIdx.y;
  int p = blockIdx.x * 256 + threadIdx.x;
  if (p >= K * N) return;
  int NT = N >> 4;
  int j = p & 7;
  int l = (p >> 3) & 63;
  int rest = p >> 9;
  int nt = rest % NT;
  int ks = rest / NT;
  int k = ks * 32 + ((l >> 4) << 3) + j;
  int n = nt * 16 + (l & 15);
  dst[mat * dstride + p] = f2bf(src[mat * sstride + (long)k * N + n]);
}

// act: [64][256] bf16 row-major, XOR-swizzled
__device__ __forceinline__ int swzA(int row, int col) {
  return ((row * DFF + col) * 2) ^ ((row & 7) << 4);
}
__device__ __forceinline__ bf16x8 ldA(const unsigned short* buf, int row, int k0) {
  return __builtin_bit_cast(bf16x8, *(const uint4*)((const char*)buf + swzA(row, k0)));
}
__device__ __forceinline__ bf16x8 ldY(const unsigned short* ybf, int row, int k0) {
  return __builtin_bit_cast(bf16x8, *(const uint4*)(ybf + row * YPITCH + k0));
}
__device__ __forceinline__ uint4 ldWraw(const unsigned short* __restrict__ wp,
                                        int ks, int NT, int ntAbs, int lane) {
  return *(const uint4*)(wp + ((((ks * NT + ntAbs) << 6) + lane) << 3));
}
__device__ __forceinline__ bf16x8 asw(uint4 v) { return __builtin_bit_cast(bf16x8, v); }

#define MFMA16(a, b, c) __builtin_amdgcn_mfma_f32_16x16x32_bf16((a), (b), (c), 0, 0, 0)

// acc[nt][rt]: features n = (ng*4+nt)*16 + lg*4 + rr, batch rows r = rt*16 + lr
__device__ __forceinline__ void biasInit(f32x4 acc[4][4], const float* __restrict__ b,
                                         int ng, int lg) {
#pragma unroll
  for (int nt = 0; nt < 4; ++nt) {
    f32x4 bv = *(const f32x4*)(b + (ng * 4 + nt) * 16 + lg * 4);
#pragma unroll
    for (int rt = 0; rt < 4; ++rt) acc[nt][rt] = bv;
  }
}

// epilogue: relu + bf16, one ds_write_b64 per (nt, rt)
__device__ __forceinline__ void storeAct(unsigned short* act, f32x4 acc[4][4],
                                         int ng, int lr, int lg) {
#pragma unroll
  for (int nt = 0; nt < 4; ++nt) {
    int n = (ng * 4 + nt) * 16 + lg * 4;
#pragma unroll
    for (int rt = 0; rt < 4; ++rt) {
      int r = rt * 16 + lr;
      bf16x4 w;
#pragma unroll
      for (int rr = 0; rr < 4; ++rr) w[rr] = (__bf16)fmaxf(acc[nt][rt][rr], 0.f);
      *(bf16x4*)((char*)act + swzA(r, n)) = w;
    }
  }
}

__global__ __launch_bounds__(THREADS, 2)
void vae_kernel(const float* __restrict__ xin, const float* __restrict__ eps,
                const float* __restrict__ be1, const float* __restrict__ be2,
                const float* __restrict__ be3, const float* __restrict__ b1,
                const float* __restrict__ b2, const float* __restrict__ W3,
                const float* __restrict__ b3,
                const unsigned short* __restrict__ We1p,
                const unsigned short* __restrict__ We2p,
                const unsigned short* __restrict__ We3p,
                const unsigned short* __restrict__ W1p,
                const unsigned short* __restrict__ W2p,
                float* __restrict__ out) {
  __shared__ __align__(16) unsigned short act[ROWS * DFF];  // 32 KB: h1/h2/zt-overlay/t1
  __shared__ unsigned short ybf[ROWS * YPITCH];             // 5 KB: masked y state, bf16
  __shared__ float yf[ROWS * YFP];                          // 8.4 KB: y state, f32
  __shared__ float red[4 * ROWS];                           // 1 KB: cross-ng W3 reduce

  // ---- phase-stagger co-resident blocks (R11: measured +5%) ----
  {
    unsigned units = ((blockIdx.x >> 8) & 1) * 2 + ((blockIdx.x >> 3) & 1);
    for (unsigned s = 0; s < units; ++s) __builtin_amdgcn_s_sleep(63);
  }

  const int tid = threadIdx.x;
  const int lane = tid & 63;
  const int ng = tid >> 6;   // wave = feature group: n in [ng*64, ng*64+63]
  const int lr = lane & 15;
  const int lg = lane >> 4;
  const long r0 = (long)blockIdx.x * ROWS;

  // ---- stage x into ybf ----
  for (int e = tid; e < ROWS * DD; e += THREADS) {
    int rr = e >> 5, d = e & 31;
    ybf[rr * YPITCH + d] = f2bf(xin[(r0 + rr) * DD + d]);
  }
  __syncthreads();

  f32x4 acc[4][4];

  // ---- enc1: h1 = relu(x @ We1 + be1) ----
  biasInit(acc, be1, ng, lg);
  {
    bf16x8 yb[4];
#pragma unroll
    for (int rt = 0; rt < 4; ++rt) yb[rt] = ldY(ybf, rt * 16 + lr, lg * 8);
#pragma unroll
    for (int nt = 0; nt < 4; ++nt) {
      bf16x8 w = asw(ldWraw(We1p, 0, 16, ng * 4 + nt, lane));
#pragma unroll
      for (int rt = 0; rt < 4; ++rt) acc[nt][rt] = MFMA16(w, yb[rt], acc[nt][rt]);
    }
  }
  storeAct(act, acc, ng, lr, lg);
  __syncthreads();

  // ---- enc2: h2 = relu(h1 @ We2 + be2), in place ----
  biasInit(acc, be2, ng, lg);
#pragma unroll
  for (int ks = 0; ks < 8; ++ks) {
    bf16x8 ab[4];
#pragma unroll
    for (int rt = 0; rt < 4; ++rt) ab[rt] = ldA(act, rt * 16 + lr, ks * 32 + lg * 8);
#pragma unroll
    for (int nt = 0; nt < 4; ++nt) {
      bf16x8 w = asw(ldWraw(We2p, ks, 16, ng * 4 + nt, lane));
#pragma unroll
      for (int rt = 0; rt < 4; ++rt) acc[nt][rt] = MFMA16(w, ab[rt], acc[nt][rt]);
    }
  }
  __syncthreads();
  storeAct(act, acc, ng, lr, lg);
  __syncthreads();

  // ---- enc3: z^T = We3^T @ h2^T + be3 -> f32 overlay zt[64][66] ----
  {
    f32x4 az[4];
    f32x4 bz = *(const f32x4*)(be3 + ng * 16 + lg * 4);
#pragma unroll
    for (int rt = 0; rt < 4; ++rt) az[rt] = bz;
#pragma unroll
    for (int ks = 0; ks < 8; ++ks) {
      bf16x8 w = asw(ldWraw(We3p, ks, 4, ng, lane));
#pragma unroll
      for (int rt = 0; rt < 4; ++rt) {
        bf16x8 a = ldA(act, rt * 16 + lr, ks * 32 + lg * 8);
        az[rt] = MFMA16(w, a, az[rt]);
      }
    }
    __syncthreads();  // all h2 reads complete before overlay write
    float* zt = (float*)act;  // [64 n][66 r] f32 = 16.9 KB
#pragma unroll
    for (int rt = 0; rt < 4; ++rt) {
      int r = rt * 16 + lr;
#pragma unroll
      for (int rr = 0; rr < 4; ++rr)
        zt[(ng * 16 + lg * 4 + rr) * 66 + r] = az[rt][rr];
    }
  }
  __syncthreads();

  // ---- reparam: y0 = mu + exp(lv/2)*eps; ybf = masked y (col 0 only) ----
  {
    const float* zt = (const float*)act;
    for (int e = tid; e < ROWS * DD; e += THREADS) {
      int rr = e >> 5, d = e & 31;
      float mu = zt[d * 66 + rr];
      float lv = zt[(32 + d) * 66 + rr];
      long gi = (r0 + rr) * DD + d;
      float y0 = mu + __expf(0.5f * lv) * eps[gi];
      yf[rr * YFP + d] = y0;
      ybf[rr * YPITCH + d] = (d == 0) ? f2bf(y0) : (unsigned short)0;
      out[BD + gi] = mu;
      out[2L * BD + gi] = lv;
    }
  }

  // ---- preload decoder weights for step 0 (overlaps reparam drain) ----
  uint4 w1f[4], w2f[4][4];
#pragma unroll
  for (int nt = 0; nt < 4; ++nt) w1f[nt] = ldWraw(W1p, 0, 16, ng * 4 + nt, lane);
#pragma unroll
  for (int ks = 0; ks < 4; ++ks)
#pragma unroll
    for (int nt = 0; nt < 4; ++nt) w2f[ks][nt] = ldWraw(W2p, ks, 16, ng * 4 + nt, lane);
  __syncthreads();

  // ---- causal decoder: 32 sequential steps, 2 barriers each ----
#pragma unroll 1
  for (int i = 0; i < DD; ++i) {
    const unsigned short* W2cur = W2p + i * (DFF * DFF);
    const int inx = (i + 1 < DD) ? i + 1 : i;
    const unsigned short* W1nx = W1p + inx * (DD * DFF);
    const unsigned short* W2nx = W2p + inx * (DFF * DFF);

    // phase A: t1 = relu(y_masked @ W1[i] + b1[i])
    biasInit(acc, b1 + i * DFF, ng, lg);
    {
      bf16x8 yb[4];
#pragma unroll
      for (int rt = 0; rt < 4; ++rt) yb[rt] = ldY(ybf, rt * 16 + lr, lg * 8);
#pragma unroll
      for (int nt = 0; nt < 4; ++nt) {
        bf16x8 w = asw(w1f[nt]);
#pragma unroll
        for (int rt = 0; rt < 4; ++rt) acc[nt][rt] = MFMA16(w, yb[rt], acc[nt][rt]);
      }
    }
    storeAct(act, acc, ng, lr, lg);
    __syncthreads();  // BAR1: t1 visible

    // phase B: t2 = relu(t1 @ W2[i] + b2[i]) in regs, fused with W3 dot.
    // Weight frags consumed from regs; each refilled right after last use.
    biasInit(acc, b2 + i * DFF, ng, lg);
#pragma unroll
    for (int ks = 0; ks < 4; ++ks) {
      bf16x8 ab[4];
#pragma unroll
      for (int rt = 0; rt < 4; ++rt) ab[rt] = ldA(act, rt * 16 + lr, ks * 32 + lg * 8);
#pragma unroll
      for (int nt = 0; nt < 4; ++nt) {
        bf16x8 w = asw(w2f[ks][nt]);
#pragma unroll
        for (int rt = 0; rt < 4; ++rt) acc[nt][rt] = MFMA16(w, ab[rt], acc[nt][rt]);
        w2f[ks][nt] = ldWraw(W2cur, ks + 4, 16, ng * 4 + nt, lane);  // refill: ks+4 of step i
      }
    }
#pragma unroll
    for (int ks = 4; ks < 8; ++ks) {
      bf16x8 ab[4];
#pragma unroll
      for (int rt = 0; rt < 4; ++rt) ab[rt] = ldA(act, rt * 16 + lr, ks * 32 + lg * 8);
#pragma unroll
      for (int nt = 0; nt < 4; ++nt) {
        bf16x8 w = asw(w2f[ks - 4][nt]);
#pragma unroll
        for (int rt = 0; rt < 4; ++rt) acc[nt][rt] = MFMA16(w, ab[rt], acc[nt][rt]);
        w2f[ks - 4][nt] = ldWraw(W2nx, ks - 4, 16, ng * 4 + nt, lane);  // refill: step i+1
      }
    }
#pragma unroll
    for (int nt = 0; nt < 4; ++nt) w1f[nt] = ldWraw(W1nx, 0, 16, ng * 4 + nt, lane);

    // fused W3 dot: out_row(i) partial per batch row
    const float* w3r = W3 + i * DFF;
    float part[4] = {0.f, 0.f, 0.f, 0.f};
#pragma unroll
    for (int nt = 0; nt < 4; ++nt) {
      f32x4 w3v = *(const f32x4*)(w3r + (ng * 4 + nt) * 16 + lg * 4);
#pragma unroll
      for (int rt = 0; rt < 4; ++rt)
#pragma unroll
        for (int rr = 0; rr < 4; ++rr)
          part[rt] = fmaf(fmaxf(acc[nt][rt][rr], 0.f), w3v[rr], part[rt]);
    }
#pragma unroll
    for (int rt = 0; rt < 4; ++rt) {
      part[rt] += __shfl_xor(part[rt], 16);
      part[rt] += __shfl_xor(part[rt], 32);
    }
    if (lg == 0) {
#pragma unroll
      for (int rt = 0; rt < 4; ++rt) red[ng * ROWS + rt * 16 + lr] = part[rt];
    }
    __syncthreads();  // BAR2: red visible

    // finalize redundantly in EVERY wave (kills BAR3): lane -> row.
    // All 4 waves compute bit-identical v (same f32 ops, same red inputs), so
    // the duplicate same-address LDS writes are benign; each wave's phase-A(i+1)
    // reads values it wrote itself -> no cross-wave ordering needed.
    {
      float v = b3[i] + red[lane] + red[ROWS + lane] + red[2 * ROWS + lane] +
                red[3 * ROWS + lane];
      yf[lane * YFP + i] = v;
      ybf[lane * YPITCH + i] = f2bf(v);
      if (i + 1 < DD)  // unmask next column (y0)
        ybf[lane * YPITCH + i + 1] = f2bf(yf[lane * YFP + i + 1]);
    }
    // no BAR3
  }

  // ---- final y -> outputs 0 and 3 ----
  for (int e = tid; e < ROWS * DD; e += THREADS) {
    int rr = e >> 5, d = e & 31;
    long gi = (r0 + rr) * DD + d;
    float v = yf[rr * YFP + d];
    out[gi] = v;
    out[3L * BD + gi] = v;
  }
}

extern "C" void kernel_launch(void* const* d_in, const int* in_sizes, int n_in,
                              void* d_out, int out_size, void* d_ws, size_t ws_size,
                              hipStream_t stream) {
  const float* xin = (const float*)d_in[0];
  // d_in[1] = m — unused by the reference
  const float* eps = (const float*)d_in[2];
  const float* We1 = (const float*)d_in[3];
  const float* be1 = (const float*)d_in[4];
  const float* We2 = (const float*)d_in[5];
  const float* be2 = (const float*)d_in[6];
  const float* We3 = (const float*)d_in[7];
  const float* be3 = (const float*)d_in[8];
  const float* W1  = (const float*)d_in[9];
  const float* b1  = (const float*)d_in[10];
  const float* W2  = (const float*)d_in[11];
  const float* b2  = (const float*)d_in[12];
  const float* W3  = (const float*)d_in[13];
  const float* b3  = (const float*)d_in[14];
  float* out = (float*)d_out;

  // packed bf16 weights in workspace (~4.9 MB)
  unsigned short* We1p = (unsigned short*)d_ws;
  unsigned short* We2p = We1p + 32 * 256;
  unsigned short* We3p = We2p + 256 * 256;
  unsigned short* W1p  = We3p + 256 * 64;
  unsigned short* W2p  = W1p + 32 * 32 * 256;

  repack_kernel<<<dim3(32, 1), 256, 0, stream>>>(We1, We1p, 32, 256, 0, 0);
  repack_kernel<<<dim3(256, 1), 256, 0, stream>>>(We2, We2p, 256, 256, 0, 0);
  repack_kernel<<<dim3(64, 1), 256, 0, stream>>>(We3, We3p, 256, 64, 0, 0);
  repack_kernel<<<dim3(32, 32), 256, 0, stream>>>(W1, W1p, 32, 256, 32 * 256, 32 * 256);
  repack_kernel<<<dim3(256, 32), 256, 0, stream>>>(W2, W2p, 256, 256, 256 * 256, 256 * 256);

  vae_kernel<<<dim3(BATCH_N / ROWS), THREADS, 0, stream>>>(
      xin, eps, be1, be2, be3, b1, b2, W3, b3, We1p, We2p, We3p, W1p, W2p, out);
}